// Round 2
// baseline (11.228 us; speedup 1.0000x reference)
//
#include <hip/hip_runtime.h>

// out[b*H + h] = in[b*C*H + idx[b]*H + h]
// B=4096, C=128, H=256, fp32.
// One wave (64 lanes) copies 4 rows: lane j moves float4 #j of each row.
// 4 independent load->store streams per thread (ILP to hide scattered-read
// latency), 64 B/thread. 4096 rows / 4 = 1024 waves = 256 blocks x 256.

__global__ __launch_bounds__(256) void gather_rows_kernel(
    const float4* __restrict__ in,   // [B, C, Hq] as float4, Hq = H/4 = 64
    const int*    __restrict__ idx,  // [B]
    float4*       __restrict__ out,  // [B, Hq] as float4
    int C, int Hq)
{
    const int tid    = blockIdx.x * blockDim.x + threadIdx.x;
    const int wave   = tid >> 6;          // global wave id
    const int lane   = tid & 63;          // float4 chunk within a row
    const int b0     = wave * 4;          // first of 4 rows this wave owns

    // 4 independent index loads (broadcast within the wave: 1 txn each)
    const int c0 = idx[b0 + 0];
    const int c1 = idx[b0 + 1];
    const int c2 = idx[b0 + 2];
    const int c3 = idx[b0 + 3];

    const size_t rowstride = (size_t)C * Hq;

    // Issue all 4 loads before any store: 4-deep memory-level parallelism.
    float4 v0 = in[(size_t)(b0 + 0) * rowstride + (size_t)c0 * Hq + lane];
    float4 v1 = in[(size_t)(b0 + 1) * rowstride + (size_t)c1 * Hq + lane];
    float4 v2 = in[(size_t)(b0 + 2) * rowstride + (size_t)c2 * Hq + lane];
    float4 v3 = in[(size_t)(b0 + 3) * rowstride + (size_t)c3 * Hq + lane];

    out[(size_t)(b0 + 0) * Hq + lane] = v0;
    out[(size_t)(b0 + 1) * Hq + lane] = v1;
    out[(size_t)(b0 + 2) * Hq + lane] = v2;
    out[(size_t)(b0 + 3) * Hq + lane] = v3;
}

extern "C" void kernel_launch(void* const* d_in, const int* in_sizes, int n_in,
                              void* d_out, int out_size, void* d_ws, size_t ws_size,
                              hipStream_t stream) {
    const float4* in  = (const float4*)d_in[0];
    const int*    idx = (const int*)d_in[1];
    float4*       out = (float4*)d_out;

    const int B  = in_sizes[1];            // 4096
    const int H  = out_size / B;           // 256
    const int Hq = H / 4;                  // 64
    const int C  = in_sizes[0] / (B * H);  // 128

    // one wave per 4 rows; 256 threads/block = 16 rows/block
    const int block = 256;
    const int grid  = B / 16;              // 256 blocks

    gather_rows_kernel<<<grid, block, 0, stream>>>(in, idx, out, C, Hq);
}

// Round 3
// 10.077 us; speedup vs baseline: 1.1142x; 1.1142x over previous
//
#include <hip/hip_runtime.h>

// out[b*H + h] = in[b*C*H + idx[b]*H + h]
// B=4096, C=128, H=256, fp32. One thread per float4 (4 floats).
// H/4 = 64 float4/row; total B*64 = 262144 threads = 1024 blocks x 256.
// R2 post-mortem: 4-rows/wave ILP variant was 11.2 us vs this at 10.05 us —
// dispatch overhead dominates (BW floor ~1.3 us); keep the simplest body.

__global__ __launch_bounds__(256) void gather_rows_kernel(
    const float4* __restrict__ in,   // [B, C, H/4] as float4
    const int*    __restrict__ idx,  // [B]
    float4*       __restrict__ out,  // [B, H/4] as float4
    int C, int Hq)                   // Hq = H/4
{
    int tid = blockIdx.x * blockDim.x + threadIdx.x;
    int b = tid / 64;   // Hq == 64
    int j = tid & 63;
    int c = idx[b];
    out[b * Hq + j] = in[(size_t)b * C * Hq + (size_t)c * Hq + j];
}

extern "C" void kernel_launch(void* const* d_in, const int* in_sizes, int n_in,
                              void* d_out, int out_size, void* d_ws, size_t ws_size,
                              hipStream_t stream) {
    const float4* in  = (const float4*)d_in[0];
    const int*    idx = (const int*)d_in[1];
    float4*       out = (float4*)d_out;

    const int B  = in_sizes[1];            // 4096
    const int H  = out_size / B;           // 256
    const int Hq = H / 4;                  // 64
    const int C  = in_sizes[0] / (B * H);  // 128

    const int total  = B * Hq;             // 262144
    const int block  = 256;
    const int grid   = (total + block - 1) / block;

    gather_rows_kernel<<<grid, block, 0, stream>>>(in, idx, out, C, Hq);
}